// Round 6
// baseline (94.514 us; speedup 1.0000x reference)
//
#include <hip/hip_runtime.h>
#include <hip/hip_cooperative_groups.h>

namespace cg = cooperative_groups;

// Problem constants (from reference setup_inputs)
#define N_  8
#define K_  32
#define TK_ 128
#define TC_ 256
#define D_  512
#define D4_ (D_ / 4)               // 128 float4 per emb row
#define TOUT_ (TK_ + TC_)          // 384
#define NEGINF_ (-1e20f)
#define INV_SQRT_D_ 0.044194173824159216f   // 1/sqrt(512)

// d_out layout (float): full_enc [N,384,512] | full_mask [N,384] | ck_attn [N,32]
#define OUT_MASK_OFF_ 1572864
#define OUT_ATTN_OFF_ 1575936

#define QPC_ 8                      // ctx slices per row (phase A pool blocks = 64)
#define QTOK_ (TC_ / QPC_)          // 32 tokens per slice
#define POOLB_ (N_ * QPC_)          // 64 pool blocks
#define NBLK_ 256
#define COPY_CHUNKS_ 256            // 2048 ctx rows / 8 rows per chunk

// ---------------------------------------------------------------
// Single cooperative kernel, 256 blocks x 1024 threads (1 block/CU).
// Phase A: ctx pooling (64 blocks) + ctx copies (192 blocks) + key reset.
// Phase B: per-(n,k) fused knowledge pool+dot -> ck_attn + atomicMax key.
// Phase C: chosen-sentence gather, 4 rows per block.
__global__ __launch_bounds__(1024) void fused_kernel(
        const int* __restrict__ src_tokens,
        const int* __restrict__ know_tokens,
        const int* __restrict__ ck_mask,
        const int* __restrict__ cs_ids,
        const int* __restrict__ use_cs_ids,
        const float* __restrict__ emb,
        float* __restrict__ full_enc,
        float* __restrict__ full_mask,
        float* __restrict__ ck_attn,
        float4* __restrict__ partial,        // [64][128] float4
        int* __restrict__ pcnt,              // [64]
        unsigned long long* __restrict__ key) {  // [8]
    cg::grid_group grid = cg::this_grid();
    const int bid = blockIdx.x;
    const int tid = threadIdx.x;
    const int tg = tid >> 7;          // 0..7
    const int lane = tid & 127;       // float4 slot within a 512-dim row
    const float4* emb4 = (const float4*)emb;

    __shared__ int s_tok[TK_];
    __shared__ float4 s_red[8][D4_];   // 16 KB
    __shared__ int s_cnt[8];
    __shared__ float4 s_ctx[D4_];      // 2 KB
    __shared__ float s_part[16];
    __shared__ int s_bcnt[2];
    __shared__ int s_chosen[N_];

    // ---------------- Phase A ----------------
    if (bid < POOLB_) {
        // pool ctx slice: row n, tokens [q*32,(q+1)*32)
        const int n = bid >> 3, q = bid & 7;
        if (bid == 0 && tid < N_) key[tid] = 0ull;   // per-call reset
        if (tid < QTOK_) s_tok[tid] = src_tokens[n * TC_ + q * QTOK_ + tid];
        __syncthreads();

        float4 acc = make_float4(0.f, 0.f, 0.f, 0.f);
        int cnt = 0;
        #pragma unroll
        for (int t = tg; t < QTOK_; t += 8) {
            const int tok = s_tok[t];
            if (tok != 0) {
                ++cnt;
                const float4 v = emb4[(size_t)tok * D4_ + lane];
                acc.x += v.x; acc.y += v.y; acc.z += v.z; acc.w += v.w;
            }
        }
        s_red[tg][lane] = acc;
        if (lane == 0) s_cnt[tg] = cnt;
        __syncthreads();

        if (tg == 0) {
            float4 tot = s_red[0][lane];
            #pragma unroll
            for (int j = 1; j < 8; ++j) {
                const float4 v = s_red[j][lane];
                tot.x += v.x; tot.y += v.y; tot.z += v.z; tot.w += v.w;
            }
            partial[bid * D4_ + lane] = tot;
            if (lane == 0) {
                int c = 0;
                #pragma unroll
                for (int j = 0; j < 8; ++j) c += s_cnt[j];
                pcnt[bid] = c;
            }
        }
    } else {
        // ctx copies: 8 rows per chunk, grid-stride over 256 chunks
        for (int c = bid - POOLB_; c < COPY_CHUNKS_; c += (NBLK_ - POOLB_)) {
            const int g = c * 8 + tg;             // ctx row 0..2047
            const int n = g >> 8, t = g & 255;
            const int tok = src_tokens[n * TC_ + t];
            ((float4*)(full_enc + ((size_t)n * TOUT_ + TK_ + t) * D_))[lane] =
                emb4[(size_t)tok * D4_ + lane];
            if (lane == 0) full_mask[n * TOUT_ + TK_ + t] = (tok != 0) ? 1.0f : 0.0f;
        }
    }

    grid.sync();

    // ---------------- Phase B: (n,k) fused knowledge pool+dot ----------------
    {
        const int n = bid >> 5, k = bid & 31;

        if (tid < D4_) {
            // combine the 8 ctx partials -> scaled ctx_use slice
            float4 c = partial[(n * QPC_ + 0) * D4_ + tid];
            int cc = pcnt[n * QPC_ + 0];
            #pragma unroll
            for (int qq = 1; qq < QPC_; ++qq) {
                const float4 v = partial[(n * QPC_ + qq) * D4_ + tid];
                c.x += v.x; c.y += v.y; c.z += v.z; c.w += v.w;
                cc += pcnt[n * QPC_ + qq];
            }
            const float sc = INV_SQRT_D_ / sqrtf((float)cc);
            c.x *= sc; c.y *= sc; c.z *= sc; c.w *= sc;
            s_ctx[tid] = c;

            const int tok = know_tokens[(size_t)bid * TK_ + tid];
            s_tok[tid] = tok;
            const unsigned long long b = __ballot(tok != 0);  // waves 0,1 full
            if ((tid & 63) == 0) s_bcnt[tid >> 6] = (int)__popcll(b);
        }
        __syncthreads();

        const float4 c = s_ctx[lane];
        float acc = 0.f;
        #pragma unroll 8
        for (int t = tg; t < TK_; t += 8) {
            const int tok = s_tok[t];
            if (tok != 0) {
                const float4 v = emb4[(size_t)tok * D4_ + lane];
                acc += v.x * c.x + v.y * c.y + v.z * c.z + v.w * c.w;
            }
        }
        #pragma unroll
        for (int off = 32; off > 0; off >>= 1) acc += __shfl_down(acc, off, 64);
        if ((tid & 63) == 0) s_part[tid >> 6] = acc;
        __syncthreads();

        if (tid == 0) {
            float v = 0.f;
            #pragma unroll
            for (int j = 0; j < 16; ++j) v += s_part[j];
            const int cnt = s_bcnt[0] + s_bcnt[1];
            v *= INV_SQRT_D_ / sqrtf((float)cnt);
            if (ck_mask[n * K_ + k] == 0) v = NEGINF_;
            ck_attn[n * K_ + k] = v;

            // order-preserving float encoding; ties -> smaller k (numpy first-max)
            unsigned ub = __float_as_uint(v);
            ub = (ub & 0x80000000u) ? ~ub : (ub | 0x80000000u);
            const unsigned long long pk =
                ((unsigned long long)ub << 32) | (unsigned)(K_ - 1 - k);
            atomicMax(&key[n], pk);
        }
    }

    grid.sync();

    // ---------------- Phase C: chosen-sentence gather ----------------
    if (tid < N_) {
        const unsigned long long kk = atomicMax(&key[tid], 0ull);  // atomic read
        const int kbest = (K_ - 1) - (int)(kk & 0xffffffffull);
        s_chosen[tid] = (use_cs_ids[0] != 0) ? cs_ids[tid] : kbest;
    }
    __syncthreads();

    if (tg < 4) {
        const int row = bid * 4 + tg;           // 0..1023
        const int n = row >> 7, r = row & 127;
        const int ch = s_chosen[n];
        const int token = know_tokens[((size_t)n * K_ + ch) * TK_ + r];
        ((float4*)(full_enc + ((size_t)n * TOUT_ + r) * D_))[lane] =
            emb4[(size_t)token * D4_ + lane];
        if (lane == 0) full_mask[n * TOUT_ + r] = (token != 0) ? 1.0f : 0.0f;
    }
}

// ---------------------------------------------------------------
extern "C" void kernel_launch(void* const* d_in, const int* in_sizes, int n_in,
                              void* d_out, int out_size, void* d_ws, size_t ws_size,
                              hipStream_t stream) {
    const int*   src_tokens  = (const int*)d_in[0];   // [N,Tc]
    const int*   know_tokens = (const int*)d_in[1];   // [N,K,Tk]
    const int*   ck_mask     = (const int*)d_in[2];   // [N,K] 0/1
    const int*   cs_ids      = (const int*)d_in[3];   // [N]
    const int*   use_cs_ids  = (const int*)d_in[4];   // scalar
    const float* emb         = (const float*)d_in[5]; // [V,D]

    float* out = (float*)d_out;
    float* full_enc  = out;
    float* full_mask = out + OUT_MASK_OFF_;
    float* ck_attn   = out + OUT_ATTN_OFF_;

    // workspace: key[8] ULL | pcnt[64] int | partial[64*128] float4
    char* ws = (char*)d_ws;
    unsigned long long* key = (unsigned long long*)ws;      // 64 B
    int* pcnt       = (int*)(ws + 64);                      // 256 B
    float4* partial = (float4*)(ws + 512);                  // 128 KB

    void* args[] = {
        (void*)&src_tokens, (void*)&know_tokens, (void*)&ck_mask,
        (void*)&cs_ids, (void*)&use_cs_ids, (void*)&emb,
        (void*)&full_enc, (void*)&full_mask, (void*)&ck_attn,
        (void*)&partial, (void*)&pcnt, (void*)&key
    };
    hipLaunchCooperativeKernel((void*)fused_kernel, dim3(NBLK_), dim3(1024),
                               args, 0, stream);
}

// Round 7
// 25.898 us; speedup vs baseline: 3.6495x; 3.6495x over previous
//
#include <hip/hip_runtime.h>

// Problem constants (from reference setup_inputs)
#define N_  8
#define K_  32
#define TK_ 128
#define TC_ 256
#define D_  512
#define D4_ (D_ / 4)               // 128 float4 per emb row
#define TOUT_ (TK_ + TC_)          // 384
#define NEGINF_ (-1e20f)
#define INV_SQRT_D_ 0.044194173824159216f   // 1/sqrt(512)

// d_out layout (float): full_enc [N,384,512] | full_mask [N,384] | ck_attn [N,32]
#define OUT_MASK_OFF_ 1572864
#define OUT_ATTN_OFF_ 1575936

#define QPC_ 8                      // ctx slices per row
#define QTOK_ (TC_ / QPC_)          // 32 tokens per slice
#define POOLB_ (N_ * QPC_)          // 64 pool blocks

// ---------------------------------------------------------------
// Kernel 1 (64 blocks x 1024): block (n,q) pools ctx tokens [q*32,(q+1)*32)
// into partial[n*8+q][128] float4 (+count). Block 0 resets key[].
// Kept minimal: this is the only thing on K2's critical path.
__global__ __launch_bounds__(1024) void ctx_pool_kernel(
        const int* __restrict__ src_tokens,
        const float* __restrict__ emb,
        float4* __restrict__ partial,        // [64][128] float4
        int* __restrict__ pcnt,              // [64]
        unsigned long long* __restrict__ key) {
    const int bid = blockIdx.x;
    const int n = bid >> 3, q = bid & 7;
    const int tid = threadIdx.x;
    const int tg = tid >> 7, lane = tid & 127;
    const float4* emb4 = (const float4*)emb;

    __shared__ int s_tok[QTOK_];
    __shared__ float4 s_red[8][D4_];   // 16 KB
    __shared__ int s_cnt[8];

    if (bid == 0 && tid < N_) key[tid] = 0ull;   // per-call reset
    if (tid < QTOK_) s_tok[tid] = src_tokens[n * TC_ + q * QTOK_ + tid];
    __syncthreads();

    float4 acc = make_float4(0.f, 0.f, 0.f, 0.f);
    int cnt = 0;
    #pragma unroll
    for (int i = 0; i < QTOK_ / 8; ++i) {        // 4 tokens per thread
        const int tok = s_tok[tg + i * 8];
        const float4 v = emb4[(size_t)tok * D4_ + lane];  // row 0 is valid
        const bool use = (tok != 0);
        cnt += use ? 1 : 0;
        acc.x += use ? v.x : 0.f;
        acc.y += use ? v.y : 0.f;
        acc.z += use ? v.z : 0.f;
        acc.w += use ? v.w : 0.f;
    }
    s_red[tg][lane] = acc;
    if (lane == 0) s_cnt[tg] = cnt;
    __syncthreads();

    if (tg == 0) {
        float4 tot = s_red[0][lane];
        #pragma unroll
        for (int j = 1; j < 8; ++j) {
            const float4 v = s_red[j][lane];
            tot.x += v.x; tot.y += v.y; tot.z += v.z; tot.w += v.w;
        }
        partial[bid * D4_ + lane] = tot;
        if (lane == 0) {
            int c = 0;
            #pragma unroll
            for (int j = 0; j < 8; ++j) c += s_cnt[j];
            pcnt[bid] = c;
        }
    }
}

// ---------------------------------------------------------------
// Kernel 2 (256 blocks x 1024): block (n,k) = fused knowledge pool+dot.
// Combine ctx partials -> s_ctx (scaled); branch-free gather-dot over 128
// token rows; scale, mask -> ck_attn + packed atomicMax argmax key[n].
__global__ __launch_bounds__(1024) void know_kernel(
        const int* __restrict__ know_tokens,
        const int* __restrict__ ck_mask,
        const float* __restrict__ emb,
        const float4* __restrict__ partial,
        const int* __restrict__ pcnt,
        float* __restrict__ ck_attn,
        unsigned long long* __restrict__ key) {
    const int bid = blockIdx.x;
    const int tid = threadIdx.x;
    const int n = bid >> 5, k = bid & 31;
    const int tg = tid >> 7, lane = tid & 127;
    const float4* emb4 = (const float4*)emb;

    __shared__ float4 s_ctx[D4_];    // 2 KB
    __shared__ int s_tok[TK_];
    __shared__ float s_part[16];
    __shared__ int s_bcnt[2];

    if (tid < D4_) {
        // combine the 8 ctx partials -> scaled ctx_use slice
        float4 c = partial[(n * QPC_ + 0) * D4_ + tid];
        int cc = pcnt[n * QPC_ + 0];
        #pragma unroll
        for (int qq = 1; qq < QPC_; ++qq) {
            const float4 v = partial[(n * QPC_ + qq) * D4_ + tid];
            c.x += v.x; c.y += v.y; c.z += v.z; c.w += v.w;
            cc += pcnt[n * QPC_ + qq];
        }
        const float sc = INV_SQRT_D_ / sqrtf((float)cc);
        c.x *= sc; c.y *= sc; c.z *= sc; c.w *= sc;
        s_ctx[tid] = c;

        const int tok = know_tokens[(size_t)bid * TK_ + tid];
        s_tok[tid] = tok;
        const unsigned long long b = __ballot(tok != 0);   // waves 0,1 full
        if ((tid & 63) == 0) s_bcnt[tid >> 6] = (int)__popcll(b);
    }
    __syncthreads();

    const float4 c = s_ctx[lane];
    float acc = 0.f;
    #pragma unroll
    for (int i = 0; i < TK_ / 8; ++i) {          // 16 tokens per thread
        const int tok = s_tok[tg + i * 8];
        const float4 v = emb4[(size_t)tok * D4_ + lane];  // unconditional load
        const float d = v.x * c.x + v.y * c.y + v.z * c.z + v.w * c.w;
        acc += (tok != 0) ? d : 0.f;             // cndmask, no branch
    }
    #pragma unroll
    for (int off = 32; off > 0; off >>= 1) acc += __shfl_down(acc, off, 64);
    if ((tid & 63) == 0) s_part[tid >> 6] = acc;
    __syncthreads();

    if (tid == 0) {
        float v = 0.f;
        #pragma unroll
        for (int j = 0; j < 16; ++j) v += s_part[j];
        const int cnt = s_bcnt[0] + s_bcnt[1];
        v *= INV_SQRT_D_ / sqrtf((float)cnt);
        if (ck_mask[n * K_ + k] == 0) v = NEGINF_;
        ck_attn[n * K_ + k] = v;

        // order-preserving float encoding; ties -> smaller k (numpy first-max)
        unsigned ub = __float_as_uint(v);
        ub = (ub & 0x80000000u) ? ~ub : (ub | 0x80000000u);
        const unsigned long long pk =
            ((unsigned long long)ub << 32) | (unsigned)(K_ - 1 - k);
        atomicMax(&key[n], pk);
    }
}

// ---------------------------------------------------------------
// Kernel 3 (3072 blocks x 128): output assembly.
// blocks [0,1024): chosen-knowledge rows (derive chosen from key[n]).
// blocks [1024,3072): context rows.
__global__ void assemble_kernel(const int* __restrict__ src_tokens,
                                const int* __restrict__ know_tokens,
                                const int* __restrict__ cs_ids,
                                const int* __restrict__ use_cs_ids,
                                const unsigned long long* __restrict__ key,
                                const float* __restrict__ emb,
                                float* __restrict__ full_enc,
                                float* __restrict__ full_mask) {
    const int bid = blockIdx.x;
    const int tid = threadIdx.x;
    const float4* emb4 = (const float4*)emb;

    int n, r, token;
    if (bid < N_ * TK_) {
        n = bid >> 7; r = bid & 127;
        const int kbest = (K_ - 1) - (int)(key[n] & 0xffffffffull);
        const int ch = (use_cs_ids[0] != 0) ? cs_ids[n] : kbest;
        token = know_tokens[((size_t)n * K_ + ch) * TK_ + r];
    } else {
        const int g = bid - N_ * TK_;     // ctx row 0..2047
        n = g >> 8; r = TK_ + (g & 255);
        token = src_tokens[n * TC_ + (g & 255)];
    }

    ((float4*)(full_enc + ((size_t)n * TOUT_ + r) * D_))[tid] =
        emb4[(size_t)token * D4_ + tid];
    if (tid == 0) full_mask[n * TOUT_ + r] = (token != 0) ? 1.0f : 0.0f;
}

// ---------------------------------------------------------------
extern "C" void kernel_launch(void* const* d_in, const int* in_sizes, int n_in,
                              void* d_out, int out_size, void* d_ws, size_t ws_size,
                              hipStream_t stream) {
    const int*   src_tokens  = (const int*)d_in[0];   // [N,Tc]
    const int*   know_tokens = (const int*)d_in[1];   // [N,K,Tk]
    const int*   ck_mask     = (const int*)d_in[2];   // [N,K] 0/1
    const int*   cs_ids      = (const int*)d_in[3];   // [N]
    const int*   use_cs_ids  = (const int*)d_in[4];   // scalar
    const float* emb         = (const float*)d_in[5]; // [V,D]

    float* out = (float*)d_out;
    float* full_enc  = out;
    float* full_mask = out + OUT_MASK_OFF_;
    float* ck_attn   = out + OUT_ATTN_OFF_;

    // workspace: key[8] ULL | pcnt[64] int | partial[64*128] float4
    char* ws = (char*)d_ws;
    unsigned long long* key = (unsigned long long*)ws;      // 64 B
    int* pcnt       = (int*)(ws + 64);                      // 256 B
    float4* partial = (float4*)(ws + 512);                  // 128 KB

    ctx_pool_kernel<<<POOLB_, 1024, 0, stream>>>(src_tokens, emb,
                                                 partial, pcnt, key);
    know_kernel<<<N_ * K_, 1024, 0, stream>>>(know_tokens, ck_mask, emb,
                                              partial, pcnt, ck_attn, key);
    assemble_kernel<<<N_ * TK_ + N_ * TC_, 128, 0, stream>>>(
        src_tokens, know_tokens, cs_ids, use_cs_ids, key, emb,
        full_enc, full_mask);
}

// Round 8
// 25.406 us; speedup vs baseline: 3.7202x; 1.0194x over previous
//
#include <hip/hip_runtime.h>

// Problem constants (from reference setup_inputs)
#define N_  8
#define K_  32
#define TK_ 128
#define TC_ 256
#define D_  512
#define D4_ (D_ / 4)               // 128 float4 per emb row
#define TOUT_ (TK_ + TC_)          // 384
#define NEGINF_ (-1e20f)
#define INV_SQRT_D_ 0.044194173824159216f   // 1/sqrt(512)

// d_out layout (float): full_enc [N,384,512] | full_mask [N,384] | ck_attn [N,32]
#define OUT_MASK_OFF_ 1572864
#define OUT_ATTN_OFF_ 1575936

#define QPC_ 8                      // ctx slices per row
#define QTOK_ (TC_ / QPC_)          // 32 tokens per slice
#define POOLB_ (N_ * QPC_)          // 64 pool blocks

// ---------------------------------------------------------------
// Kernel 1 (64 blocks x 1024): block (n,q) handles ctx tokens
// [q*32,(q+1)*32): pools them into partial[n*8+q] (+count) AND writes the
// corresponding full_enc context rows + full_mask while the data is in
// registers (kills the redundant re-gather that K3 used to do).
// Block 0 resets key[].
__global__ __launch_bounds__(1024) void ctx_pool_kernel(
        const int* __restrict__ src_tokens,
        const float* __restrict__ emb,
        float* __restrict__ full_enc,
        float* __restrict__ full_mask,
        float4* __restrict__ partial,        // [64][128] float4
        int* __restrict__ pcnt,              // [64]
        unsigned long long* __restrict__ key) {
    const int bid = blockIdx.x;
    const int n = bid >> 3, q = bid & 7;
    const int tid = threadIdx.x;
    const int tg = tid >> 7, lane = tid & 127;
    const float4* emb4 = (const float4*)emb;

    __shared__ int s_tok[QTOK_];
    __shared__ float4 s_red[8][D4_];   // 16 KB
    __shared__ int s_cnt[8];

    if (bid == 0 && tid < N_) key[tid] = 0ull;   // per-call reset
    if (tid < QTOK_) s_tok[tid] = src_tokens[n * TC_ + q * QTOK_ + tid];
    __syncthreads();

    float4 acc = make_float4(0.f, 0.f, 0.f, 0.f);
    int cnt = 0;
    #pragma unroll
    for (int i = 0; i < QTOK_ / 8; ++i) {        // 4 tokens per thread
        const int t = tg + i * 8;                // token slot within slice
        const int tok = s_tok[t];
        const float4 v = emb4[(size_t)tok * D4_ + lane];  // row 0 is valid
        // write-through to full_enc context region (emb[tok] regardless of pad)
        const int row = TK_ + q * QTOK_ + t;
        ((float4*)(full_enc + ((size_t)n * TOUT_ + row) * D_))[lane] = v;
        if (lane == 0) full_mask[n * TOUT_ + row] = (tok != 0) ? 1.0f : 0.0f;

        const bool use = (tok != 0);
        cnt += use ? 1 : 0;
        acc.x += use ? v.x : 0.f;
        acc.y += use ? v.y : 0.f;
        acc.z += use ? v.z : 0.f;
        acc.w += use ? v.w : 0.f;
    }
    s_red[tg][lane] = acc;
    if (lane == 0) s_cnt[tg] = cnt;
    __syncthreads();

    if (tg == 0) {
        float4 tot = s_red[0][lane];
        #pragma unroll
        for (int j = 1; j < 8; ++j) {
            const float4 v = s_red[j][lane];
            tot.x += v.x; tot.y += v.y; tot.z += v.z; tot.w += v.w;
        }
        partial[bid * D4_ + lane] = tot;
        if (lane == 0) {
            int c = 0;
            #pragma unroll
            for (int j = 0; j < 8; ++j) c += s_cnt[j];
            pcnt[bid] = c;
        }
    }
}

// ---------------------------------------------------------------
// Kernel 2 (256 blocks x 1024): block (n,k) = fused knowledge pool+dot.
// Combine ctx partials -> s_ctx (scaled); branch-free gather-dot over 128
// token rows; scale, mask -> ck_attn + packed atomicMax argmax key[n].
__global__ __launch_bounds__(1024) void know_kernel(
        const int* __restrict__ know_tokens,
        const int* __restrict__ ck_mask,
        const float* __restrict__ emb,
        const float4* __restrict__ partial,
        const int* __restrict__ pcnt,
        float* __restrict__ ck_attn,
        unsigned long long* __restrict__ key) {
    const int bid = blockIdx.x;
    const int tid = threadIdx.x;
    const int n = bid >> 5, k = bid & 31;
    const int tg = tid >> 7, lane = tid & 127;
    const float4* emb4 = (const float4*)emb;

    __shared__ float4 s_ctx[D4_];    // 2 KB
    __shared__ int s_tok[TK_];
    __shared__ float s_part[16];
    __shared__ int s_bcnt[2];

    if (tid < D4_) {
        // combine the 8 ctx partials -> scaled ctx_use slice
        float4 c = partial[(n * QPC_ + 0) * D4_ + tid];
        int cc = pcnt[n * QPC_ + 0];
        #pragma unroll
        for (int qq = 1; qq < QPC_; ++qq) {
            const float4 v = partial[(n * QPC_ + qq) * D4_ + tid];
            c.x += v.x; c.y += v.y; c.z += v.z; c.w += v.w;
            cc += pcnt[n * QPC_ + qq];
        }
        const float sc = INV_SQRT_D_ / sqrtf((float)cc);
        c.x *= sc; c.y *= sc; c.z *= sc; c.w *= sc;
        s_ctx[tid] = c;

        const int tok = know_tokens[(size_t)bid * TK_ + tid];
        s_tok[tid] = tok;
        const unsigned long long b = __ballot(tok != 0);   // waves 0,1 full
        if ((tid & 63) == 0) s_bcnt[tid >> 6] = (int)__popcll(b);
    }
    __syncthreads();

    const float4 c = s_ctx[lane];
    float acc = 0.f;
    #pragma unroll
    for (int i = 0; i < TK_ / 8; ++i) {          // 16 tokens per thread
        const int tok = s_tok[tg + i * 8];
        const float4 v = emb4[(size_t)tok * D4_ + lane];  // unconditional load
        const float d = v.x * c.x + v.y * c.y + v.z * c.z + v.w * c.w;
        acc += (tok != 0) ? d : 0.f;             // cndmask, no branch
    }
    #pragma unroll
    for (int off = 32; off > 0; off >>= 1) acc += __shfl_down(acc, off, 64);
    if ((tid & 63) == 0) s_part[tid >> 6] = acc;
    __syncthreads();

    if (tid == 0) {
        float v = 0.f;
        #pragma unroll
        for (int j = 0; j < 16; ++j) v += s_part[j];
        const int cnt = s_bcnt[0] + s_bcnt[1];
        v *= INV_SQRT_D_ / sqrtf((float)cnt);
        if (ck_mask[n * K_ + k] == 0) v = NEGINF_;
        ck_attn[n * K_ + k] = v;

        // order-preserving float encoding; ties -> smaller k (numpy first-max)
        unsigned ub = __float_as_uint(v);
        ub = (ub & 0x80000000u) ? ~ub : (ub | 0x80000000u);
        const unsigned long long pk =
            ((unsigned long long)ub << 32) | (unsigned)(K_ - 1 - k);
        atomicMax(&key[n], pk);
    }
}

// ---------------------------------------------------------------
// Kernel 3 (1024 blocks x 128): chosen-knowledge rows only.
// Each block derives chosen from key[n] (finalized at K2 kernel boundary)
// and copies one emb row into full_enc + writes its mask bit.
__global__ void gather_cs_kernel(const int* __restrict__ know_tokens,
                                 const int* __restrict__ cs_ids,
                                 const int* __restrict__ use_cs_ids,
                                 const unsigned long long* __restrict__ key,
                                 const float* __restrict__ emb,
                                 float* __restrict__ full_enc,
                                 float* __restrict__ full_mask) {
    const int bid = blockIdx.x;
    const int n = bid >> 7;
    const int r = bid & 127;
    const int tid = threadIdx.x;

    const int kbest = (K_ - 1) - (int)(key[n] & 0xffffffffull);
    const int ch = (use_cs_ids[0] != 0) ? cs_ids[n] : kbest;

    const int token = know_tokens[((size_t)n * K_ + ch) * TK_ + r];
    ((float4*)(full_enc + ((size_t)n * TOUT_ + r) * D_))[tid] =
        ((const float4*)(emb + (size_t)token * D_))[tid];
    if (tid == 0) full_mask[n * TOUT_ + r] = (token != 0) ? 1.0f : 0.0f;
}

// ---------------------------------------------------------------
extern "C" void kernel_launch(void* const* d_in, const int* in_sizes, int n_in,
                              void* d_out, int out_size, void* d_ws, size_t ws_size,
                              hipStream_t stream) {
    const int*   src_tokens  = (const int*)d_in[0];   // [N,Tc]
    const int*   know_tokens = (const int*)d_in[1];   // [N,K,Tk]
    const int*   ck_mask     = (const int*)d_in[2];   // [N,K] 0/1
    const int*   cs_ids      = (const int*)d_in[3];   // [N]
    const int*   use_cs_ids  = (const int*)d_in[4];   // scalar
    const float* emb         = (const float*)d_in[5]; // [V,D]

    float* out = (float*)d_out;
    float* full_enc  = out;
    float* full_mask = out + OUT_MASK_OFF_;
    float* ck_attn   = out + OUT_ATTN_OFF_;

    // workspace: key[8] ULL | pcnt[64] int | partial[64*128] float4
    char* ws = (char*)d_ws;
    unsigned long long* key = (unsigned long long*)ws;      // 64 B
    int* pcnt       = (int*)(ws + 64);                      // 256 B
    float4* partial = (float4*)(ws + 512);                  // 128 KB

    ctx_pool_kernel<<<POOLB_, 1024, 0, stream>>>(src_tokens, emb,
                                                 full_enc, full_mask,
                                                 partial, pcnt, key);
    know_kernel<<<N_ * K_, 1024, 0, stream>>>(know_tokens, ck_mask, emb,
                                              partial, pcnt, ck_attn, key);
    gather_cs_kernel<<<N_ * TK_, 128, 0, stream>>>(know_tokens, cs_ids,
                                                   use_cs_ids, key, emb,
                                                   full_enc, full_mask);
}